// Round 20
// baseline (67.196 us; speedup 1.0000x reference)
//
#include <hip/hip_runtime.h>
#include <hip/hip_bf16.h>
#include <math.h>

#define CIN   64
#define COUT  32
#define K1V   17
#define HV    4
#define BTILE 3           // bt slices per gcn block (24 = 8 tiles x 3)
#define NXCD  8

typedef float v4f __attribute__((ext_vector_type(4)));
typedef unsigned int v4u __attribute__((ext_vector_type(4)));
typedef short bf8s __attribute__((ext_vector_type(8)));   // 8 bf16 = 4 VGPRs (MFMA A/B frag)
typedef float f32x16 __attribute__((ext_vector_type(16)));
typedef unsigned short u16;

__device__ __forceinline__ float bf2f(u16 h) {
  unsigned u = ((unsigned)h) << 16;
  return __builtin_bit_cast(float, u);
}
__device__ __forceinline__ unsigned cvt2(float lo, float hi) {
  __hip_bfloat162 p = __float22bfloat162_rn(make_float2(lo, hi));
  unsigned u;
  __builtin_memcpy(&u, &p, 4);
  return u;
}
__device__ __forceinline__ bf8s pack8(v4f a, v4f b) {
  v4u u = { cvt2(a.x, a.y), cvt2(a.z, a.w), cvt2(b.x, b.y), cvt2(b.z, b.w) };
  return __builtin_bit_cast(bf8s, u);
}
__device__ __forceinline__ u16 f2bf(float f) {
  __hip_bfloat16 h = __float2bfloat16(f);
  u16 u;
  __builtin_memcpy(&u, &h, 2);
  return u;
}

// Kernel A (MFMA, zero-LDS, tile-interleaved xp — R19):
//   xp[((jt*N + n)*3 + t)*32 + o],  bt = jt*3 + t.
// C/D (m74/m101): col=lane&31, row=(reg&3)+8*(reg>>2)+4*(lane>>5).
__global__ __launch_bounds__(256, 4) void proj_kernel(
    const float* __restrict__ x, const float* __restrict__ W,
    const float* __restrict__ b, u16* __restrict__ xp, long nrows, int N) {
  int tid = threadIdx.x;
  int wv  = tid >> 6;
  int l   = tid & 63;
  int lr  = l & 31;
  int lh  = l >> 5;
  long rbase = (long)blockIdx.x * 128 + wv * 32;   // M = 240000 = 1875*128
  if (rbase + lr >= nrows) return;

  const float* xr = x + (rbase + lr) * CIN + lh * 8;
  const float* wr = W + (long)lr * CIN + lh * 8;

  bf8s afr[4], bfr[4];
#pragma unroll
  for (int ks = 0; ks < 4; ++ks) {
    v4f xa = *(const v4f*)(xr + ks * 16);
    v4f xb = *(const v4f*)(xr + ks * 16 + 4);
    v4f wa = *(const v4f*)(wr + ks * 16);
    v4f wb = *(const v4f*)(wr + ks * 16 + 4);
    afr[ks] = pack8(xa, xb);
    bfr[ks] = pack8(wa, wb);
  }

  f32x16 acc;
#pragma unroll
  for (int i = 0; i < 16; ++i) acc[i] = 0.0f;
#pragma unroll
  for (int ks = 0; ks < 4; ++ks)
    acc = __builtin_amdgcn_mfma_f32_32x32x16_bf16(afr[ks], bfr[ks], acc, 0, 0, 0);

  float bias = b[lr];
  int bt0  = (int)(rbase / N);
  int rem0 = (int)(rbase - (long)bt0 * N);
#pragma unroll
  for (int r = 0; r < 16; ++r) {
    int rr = (r & 3) + 8 * (r >> 2) + 4 * lh;
    int n  = rem0 + rr;
    int bt = bt0;
    if (n >= N) { n -= N; bt += 1; }
    int j  = (bt * 21846) >> 16;                // bt/3, exact for bt < 24
    int t  = bt - 3 * j;
    size_t off = ((size_t)((long)j * N + n) * 3 + t) * 32 + lr;
    xp[off] = f2bf(acc[r] + bias);
  }
}

// Kernel C (R15 body + one-atomic XCD confinement): ngroups*8 blocks, each
// takes ONE item. XCD q owns jt-tile q (items [q*perq,(q+1)*perq)) -> its
// 1.92MB xp window is gathered only through its own L2 (R12 proved FETCH
// 149->24MB; R12's cost was per-ITEM queue atomics — here it's 1/block).
// Probe-overshoot is safe: whoever receives r<perq does that item; coverage
// exact, output deterministic.
__global__ __launch_bounds__(256) void gcn_kernel(
    const u16*   __restrict__ xp,    // (8, N, 3, 32) bf16 interleaved
    const float* __restrict__ dist,  // (N, K1)
    const int*   __restrict__ nn,    // (N, K1)
    float* __restrict__ out,         // (BT, N, H, 32)
    int*   __restrict__ ctr,         // 8 counters, 64B apart
    int N, int ngroups, int perq, int nitems) {
  __shared__ float wl[8][K1V][HV];
  __shared__ float dl[8][K1V];
  __shared__ int   nl[8][K1V];
  __shared__ float dagl[8][HV];
  __shared__ int   s_item;

  int tid = threadIdx.x;
  if (tid == 0) {
    int xcc = __builtin_amdgcn_s_getreg(63508) & (NXCD - 1);  // HW_REG_XCC_ID
    int item = -1;
    for (int a = 0; a < NXCD; ++a) {
      int q = (xcc + a) & (NXCD - 1);
      int r = atomicAdd(&ctr[q * 16], 1);
      if (r < perq) {
        int cand = q * perq + r;
        if (cand < nitems) { item = cand; break; }
      }
    }
    s_item = item;
  }
  __syncthreads();
  int item = s_item;
  if (item < 0) return;

  int jt  = item / ngroups;        // XCD-owned bt tile
  int n0  = (item - jt * ngroups) * 8;
  int bt0 = jt * BTILE;

  if (tid < 8 * K1V) {        // 136 builder threads
    int l = tid / K1V, k = tid % K1V;
    int n_ = n0 + l;
    float w0 = 0, w1 = 0, w2 = 0, w3 = 0, dc = 0;
    int idx = 0;
    if (n_ < N) {
      float d = dist[(long)n_ * K1V + k];
      idx = nn[(long)n_ * K1V + k];
      float d2 = d * d;
      w0 = __expf(-d2 * 0.25f);
      w1 = __expf(-d2 * 0.50f);
      w2 = __expf(-d2 * 0.75f);
      w3 = __expf(-d2);
      if (idx == -1) { w0 = w1 = w2 = w3 = 0.0f; }
      if (w0 < 1e-5f) w0 = 0.0f;
      if (w1 < 1e-5f) w1 = 0.0f;
      if (w2 < 1e-5f) w2 = 0.0f;
      if (w3 < 1e-5f) w3 = 0.0f;
      dc = isinf(d) ? 0.0f : d;
      if (idx < 0 || idx >= N) idx = 0;   // its w==0; safe address
    }
    wl[l][k][0] = w0; wl[l][k][1] = w1; wl[l][k][2] = w2; wl[l][k][3] = w3;
    dl[l][k] = dc; nl[l][k] = idx;
  }
  __syncthreads();

  if (tid < 8 * HV) {         // fold dist_agg once per (node, head)
    int l = tid >> 2, h = tid & 3;
    float s = 0.0f;
#pragma unroll
    for (int k = 0; k < K1V; ++k) s = fmaf(wl[l][k][h], dl[l][k], s);
    dagl[l][h] = s;
  }
  __syncthreads();

  int ln = tid >> 5;          // local node
  int c  = tid & 31;          // channel
  int n  = n0 + ln;
  if (n >= N) return;

  int off[K1V];
#pragma unroll
  for (int k = 0; k < K1V; ++k) off[k] = nl[ln][k] * (BTILE * COUT);

  const u16* base = xp + (size_t)jt * N * (BTILE * COUT) + c;

  float a[BTILE][HV];
#pragma unroll
  for (int t = 0; t < BTILE; ++t) {
    a[t][0] = dagl[ln][0]; a[t][1] = dagl[ln][1];
    a[t][2] = dagl[ln][2]; a[t][3] = dagl[ln][3];
  }

#pragma unroll
  for (int k = 0; k < K1V; ++k) {
    float v0 = bf2f(base[off[k]]);
    float v1 = bf2f(base[off[k] + COUT]);
    float v2 = bf2f(base[off[k] + 2 * COUT]);
    v4f w4 = *(const v4f*)&wl[ln][k][0];
    a[0][0] = fmaf(w4.x, v0, a[0][0]);
    a[0][1] = fmaf(w4.y, v0, a[0][1]);
    a[0][2] = fmaf(w4.z, v0, a[0][2]);
    a[0][3] = fmaf(w4.w, v0, a[0][3]);
    a[1][0] = fmaf(w4.x, v1, a[1][0]);
    a[1][1] = fmaf(w4.y, v1, a[1][1]);
    a[1][2] = fmaf(w4.z, v1, a[1][2]);
    a[1][3] = fmaf(w4.w, v1, a[1][3]);
    a[2][0] = fmaf(w4.x, v2, a[2][0]);
    a[2][1] = fmaf(w4.y, v2, a[2][1]);
    a[2][2] = fmaf(w4.z, v2, a[2][2]);
    a[2][3] = fmaf(w4.w, v2, a[2][3]);
  }

#pragma unroll
  for (int t = 0; t < BTILE; ++t) {
    float* ob = out + (((size_t)(bt0 + t) * N + n) * HV) * COUT + c;
    __builtin_nontemporal_store(a[t][0], ob);
    __builtin_nontemporal_store(a[t][1], ob + COUT);
    __builtin_nontemporal_store(a[t][2], ob + 2 * COUT);
    __builtin_nontemporal_store(a[t][3], ob + 3 * COUT);
  }
}

extern "C" void kernel_launch(void* const* d_in, const int* in_sizes, int n_in,
                              void* d_out, int out_size, void* d_ws, size_t ws_size,
                              hipStream_t stream) {
  const float* x    = (const float*)d_in[0];
  const float* W    = (const float*)d_in[1];
  const float* b    = (const float*)d_in[2];
  const float* dist = (const float*)d_in[3];
  const int*   nn   = (const int*)d_in[4];
  float* out = (float*)d_out;

  // ws: [0,512): 8 counters @64B | [512,...): xp (15.36 MB)
  int* ctr = (int*)d_ws;
  u16* xp  = (u16*)((char*)d_ws + 512);

  int  N  = in_sizes[4] / K1V;                 // 10000
  long M  = (long)in_sizes[0] / CIN;           // BT * N = 240000
  int  BT = (int)(M / N);                      // 24

  hipMemsetAsync(ctr, 0, 512, stream);

  proj_kernel<<<(int)((M + 127) / 128), 256, 0, stream>>>(x, W, b, xp, M, N);

  int ngroups = (N + 7) / 8;                   // 1250
  int njt     = BT / BTILE;                    // 8
  int nitems  = ngroups * njt;                 // 10000
  int perq    = (nitems + NXCD - 1) / NXCD;    // 1250 (jt q -> XCD q exactly)
  gcn_kernel<<<nitems, 256, 0, stream>>>(xp, dist, nn, out, ctr,
                                         N, ngroups, perq, nitems);
}

// Round 21
// 61.175 us; speedup vs baseline: 1.0984x; 1.0984x over previous
//
#include <hip/hip_runtime.h>
#include <hip/hip_bf16.h>
#include <math.h>

#define CIN   64
#define COUT  32
#define K1V   17
#define HV    4
#define BTILE 3           // bt slices per gcn block (24 = 8 tiles x 3)

typedef float v4f __attribute__((ext_vector_type(4)));
typedef unsigned int v4u __attribute__((ext_vector_type(4)));
typedef short bf8s __attribute__((ext_vector_type(8)));   // 8 bf16 = 4 VGPRs (MFMA A/B frag)
typedef float f32x16 __attribute__((ext_vector_type(16)));
typedef unsigned short u16;

__device__ __forceinline__ float bf2f(u16 h) {
  unsigned u = ((unsigned)h) << 16;
  return __builtin_bit_cast(float, u);
}
__device__ __forceinline__ unsigned cvt2(float lo, float hi) {
  __hip_bfloat162 p = __float22bfloat162_rn(make_float2(lo, hi));
  unsigned u;
  __builtin_memcpy(&u, &p, 4);
  return u;
}
__device__ __forceinline__ bf8s pack8(v4f a, v4f b) {
  v4u u = { cvt2(a.x, a.y), cvt2(a.z, a.w), cvt2(b.x, b.y), cvt2(b.z, b.w) };
  return __builtin_bit_cast(bf8s, u);
}
__device__ __forceinline__ u16 f2bf(float f) {
  __hip_bfloat16 h = __float2bfloat16(f);
  u16 u;
  __builtin_memcpy(&u, &h, 2);
  return u;
}

// Kernel A (MFMA, zero-LDS, tile-interleaved xp — R19 best):
//   xp[((jt*N + n)*3 + t)*32 + o],  bt = jt*3 + t.
// Wave computes one 32x32 tile with 4x mfma_f32_32x32x16_bf16; A/B frags
// loaded directly from global (8 contiguous fp32 per lane) + v_cvt_pk.
// C/D (m74/m101): col=lane&31, row=(reg&3)+8*(reg>>2)+4*(lane>>5).
__global__ __launch_bounds__(256, 4) void proj_kernel(
    const float* __restrict__ x, const float* __restrict__ W,
    const float* __restrict__ b, u16* __restrict__ xp, long nrows, int N) {
  int tid = threadIdx.x;
  int wv  = tid >> 6;
  int l   = tid & 63;
  int lr  = l & 31;
  int lh  = l >> 5;
  long rbase = (long)blockIdx.x * 128 + wv * 32;   // M = 240000 = 1875*128
  if (rbase + lr >= nrows) return;

  const float* xr = x + (rbase + lr) * CIN + lh * 8;
  const float* wr = W + (long)lr * CIN + lh * 8;

  bf8s afr[4], bfr[4];
#pragma unroll
  for (int ks = 0; ks < 4; ++ks) {
    v4f xa = *(const v4f*)(xr + ks * 16);
    v4f xb = *(const v4f*)(xr + ks * 16 + 4);
    v4f wa = *(const v4f*)(wr + ks * 16);
    v4f wb = *(const v4f*)(wr + ks * 16 + 4);
    afr[ks] = pack8(xa, xb);
    bfr[ks] = pack8(wa, wb);
  }

  f32x16 acc;
#pragma unroll
  for (int i = 0; i < 16; ++i) acc[i] = 0.0f;
#pragma unroll
  for (int ks = 0; ks < 4; ++ks)
    acc = __builtin_amdgcn_mfma_f32_32x32x16_bf16(afr[ks], bfr[ks], acc, 0, 0, 0);

  float bias = b[lr];
  int bt0  = (int)(rbase / N);
  int rem0 = (int)(rbase - (long)bt0 * N);
#pragma unroll
  for (int r = 0; r < 16; ++r) {
    int rr = (r & 3) + 8 * (r >> 2) + 4 * lh;   // row within 32-row tile
    int n  = rem0 + rr;
    int bt = bt0;
    if (n >= N) { n -= N; bt += 1; }            // tile may straddle one bt edge
    int j  = (bt * 21846) >> 16;                // bt/3, exact for bt < 24
    int t  = bt - 3 * j;
    size_t off = ((size_t)((long)j * N + n) * 3 + t) * 32 + lr;
    xp[off] = f2bf(acc[r] + bias);              // 32 lanes -> 64B contiguous
  }
}

// Kernel C (R15 structure + interleaved xp — R19 best): grid (node_groups,
// 8 jt-tiles), x fastest -> co-resident blocks share a 1.92MB window.
// Table built once per block; per k: 3 gathers within one 192B node-row
// (v1/v2 L1-hit) feed 12 FMAs; 12 coalesced nt stores.
__global__ __launch_bounds__(256) void gcn_kernel(
    const u16*   __restrict__ xp,    // (8, N, 3, 32) bf16 interleaved
    const float* __restrict__ dist,  // (N, K1)
    const int*   __restrict__ nn,    // (N, K1)
    float* __restrict__ out,         // (BT, N, H, 32)
    int N) {
  __shared__ float wl[8][K1V][HV];
  __shared__ float dl[8][K1V];
  __shared__ int   nl[8][K1V];
  __shared__ float dagl[8][HV];

  int tid = threadIdx.x;
  int jt  = blockIdx.y;            // bt tile: bt = jt*3 + t
  int bt0 = jt * BTILE;
  int n0  = blockIdx.x * 8;

  if (tid < 8 * K1V) {        // 136 builder threads
    int l = tid / K1V, k = tid % K1V;
    int n_ = n0 + l;
    float w0 = 0, w1 = 0, w2 = 0, w3 = 0, dc = 0;
    int idx = 0;
    if (n_ < N) {
      float d = dist[(long)n_ * K1V + k];
      idx = nn[(long)n_ * K1V + k];
      float d2 = d * d;
      w0 = __expf(-d2 * 0.25f);
      w1 = __expf(-d2 * 0.50f);
      w2 = __expf(-d2 * 0.75f);
      w3 = __expf(-d2);
      if (idx == -1) { w0 = w1 = w2 = w3 = 0.0f; }
      if (w0 < 1e-5f) w0 = 0.0f;
      if (w1 < 1e-5f) w1 = 0.0f;
      if (w2 < 1e-5f) w2 = 0.0f;
      if (w3 < 1e-5f) w3 = 0.0f;
      dc = isinf(d) ? 0.0f : d;
      if (idx < 0 || idx >= N) idx = 0;   // its w==0; safe address
    }
    wl[l][k][0] = w0; wl[l][k][1] = w1; wl[l][k][2] = w2; wl[l][k][3] = w3;
    dl[l][k] = dc; nl[l][k] = idx;
  }
  __syncthreads();

  if (tid < 8 * HV) {         // fold dist_agg once per (node, head)
    int l = tid >> 2, h = tid & 3;
    float s = 0.0f;
#pragma unroll
    for (int k = 0; k < K1V; ++k) s = fmaf(wl[l][k][h], dl[l][k], s);
    dagl[l][h] = s;
  }
  __syncthreads();

  int ln = tid >> 5;          // local node
  int c  = tid & 31;          // channel
  int n  = n0 + ln;
  if (n >= N) return;

  int off[K1V];               // element offsets within this tile's xp block
#pragma unroll
  for (int k = 0; k < K1V; ++k) off[k] = nl[ln][k] * (BTILE * COUT);

  const u16* base = xp + (size_t)jt * N * (BTILE * COUT) + c;

  float a[BTILE][HV];
#pragma unroll
  for (int t = 0; t < BTILE; ++t) {
    a[t][0] = dagl[ln][0]; a[t][1] = dagl[ln][1];
    a[t][2] = dagl[ln][2]; a[t][3] = dagl[ln][3];
  }

#pragma unroll
  for (int k = 0; k < K1V; ++k) {
    float v0 = bf2f(base[off[k]]);          // same 192B node-row:
    float v1 = bf2f(base[off[k] + COUT]);   //   v1, v2 are L1 hits
    float v2 = bf2f(base[off[k] + 2 * COUT]);
    v4f w4 = *(const v4f*)&wl[ln][k][0];
    a[0][0] = fmaf(w4.x, v0, a[0][0]);
    a[0][1] = fmaf(w4.y, v0, a[0][1]);
    a[0][2] = fmaf(w4.z, v0, a[0][2]);
    a[0][3] = fmaf(w4.w, v0, a[0][3]);
    a[1][0] = fmaf(w4.x, v1, a[1][0]);
    a[1][1] = fmaf(w4.y, v1, a[1][1]);
    a[1][2] = fmaf(w4.z, v1, a[1][2]);
    a[1][3] = fmaf(w4.w, v1, a[1][3]);
    a[2][0] = fmaf(w4.x, v2, a[2][0]);
    a[2][1] = fmaf(w4.y, v2, a[2][1]);
    a[2][2] = fmaf(w4.z, v2, a[2][2]);
    a[2][3] = fmaf(w4.w, v2, a[2][3]);
  }

#pragma unroll
  for (int t = 0; t < BTILE; ++t) {
    float* ob = out + (((size_t)(bt0 + t) * N + n) * HV) * COUT + c;
    __builtin_nontemporal_store(a[t][0], ob);
    __builtin_nontemporal_store(a[t][1], ob + COUT);
    __builtin_nontemporal_store(a[t][2], ob + 2 * COUT);
    __builtin_nontemporal_store(a[t][3], ob + 3 * COUT);
  }
}

extern "C" void kernel_launch(void* const* d_in, const int* in_sizes, int n_in,
                              void* d_out, int out_size, void* d_ws, size_t ws_size,
                              hipStream_t stream) {
  const float* x    = (const float*)d_in[0];
  const float* W    = (const float*)d_in[1];
  const float* b    = (const float*)d_in[2];
  const float* dist = (const float*)d_in[3];
  const int*   nn   = (const int*)d_in[4];
  float* out = (float*)d_out;
  u16*   xp  = (u16*)d_ws;     // (8, N, 3, 32) bf16 = 15.36 MB

  int  N  = in_sizes[4] / K1V;                 // 10000
  long M  = (long)in_sizes[0] / CIN;           // BT * N = 240000
  int  BT = (int)(M / N);                      // 24

  proj_kernel<<<(int)((M + 127) / 128), 256, 0, stream>>>(x, W, b, xp, M, N);

  dim3 grid((N + 7) / 8, BT / BTILE);          // 1250 x 8, x fastest
  gcn_kernel<<<grid, 256, 0, stream>>>(xp, dist, nn, out, N);
}